// Round 5
// baseline (219.899 us; speedup 1.0000x reference)
//
#include <hip/hip_runtime.h>

#define NEG_SLOPE 0.2f

__device__ __forceinline__ float leaky(float v) { return v > 0.f ? v : NEG_SLOPE * v; }
__device__ __forceinline__ float relu_f(float v) { return v > 0.f ? v : 0.f; }

// Block = 512 threads = 8 waves, 64 samples per block, 8 threads per sample.
// All work-splitting lives in the WAVE index so it is provably uniform:
//   GAT phase : wave w -> g = w&1 (graph), c4 = w>>1 (channel quarter, 4 ch each)
//               lane   -> sample-in-block. Weights indexed by (c4, const) -> SGPR.
//               Live set ~55-60 VGPR -> fits the 64-reg allocation with NO spill
//               (R2-R4 lesson: xl+xr for 16 channels = 96+ regs always spilled).
//   MLP phase : wave w -> q = w (16 hidden units), lane -> sample. W1/W2 scalar.
//               Partials combined via ds_add_f32 into padded LDS.
// LDS: lp exchange [2][4][64][9] (stride 9 -> conflict-free), h [64][33],
//      o [64][33] (stride 33 -> conflict-free). Total ~35 KB -> 4 blocks/CU.
__global__ __launch_bounds__(512)
void scl_fused_kernel(
    const float* __restrict__ agent_pos, const float* __restrict__ agent_vel,
    const float* __restrict__ rel_lm, const float* __restrict__ other_pos,
    const float* __restrict__ lm_pos,
    const float* __restrict__ Wl, const float* __restrict__ bl,
    const float* __restrict__ Wr, const float* __restrict__ br,
    const float* __restrict__ We, const float* __restrict__ att,
    const float* __restrict__ bias,
    const float* __restrict__ W1, const float* __restrict__ b1,
    const float* __restrict__ W2, const float* __restrict__ b2,
    float* __restrict__ out, int Btot)
{
    __shared__ float lds_lp[2][4][64][9];   // [g][c4][sample][edge]
    __shared__ float lds_h[64][33];         // pooled GAT outputs, stride 33
    __shared__ float lds_o[64][33];         // MLP partial accumulators, stride 33

    const int tid  = threadIdx.x;
    const int lane = tid & 63;              // sample-in-block
    const int w    = tid >> 6;
    const int g    = __builtin_amdgcn_readfirstlane(w & 1);
    const int c4   = __builtin_amdgcn_readfirstlane(w >> 1);
    const int q    = __builtin_amdgcn_readfirstlane(w);
    const int CB   = c4 * 4;                // channel base (uniform)

    int b = blockIdx.x * 64 + lane;
    if (b >= Btot) b = Btot - 1;            // clamp reads; barriers stay uniform

    // ---- zero my slice of lds_o (64x32 entries / 512 threads = 4 each) ----
    {
        int i0 = tid * 4;                   // 0..2044, 4 consecutive in one row
        int r = i0 >> 5, c = i0 & 31;
        lds_o[r][c + 0] = 0.f; lds_o[r][c + 1] = 0.f;
        lds_o[r][c + 2] = 0.f; lds_o[r][c + 3] = 0.f;
    }

    const int o0[3] = {1, 0, 0};
    const int o1[3] = {2, 2, 1};

    // ---- positions (uniform branch) ----
    float px[3], py[3];
    if (g == 0) {
        const float2* ap = reinterpret_cast<const float2*>(agent_pos + b * 6);
#pragma unroll
        for (int j = 0; j < 3; ++j) { px[j] = ap[j].x; py[j] = ap[j].y; }
    } else {
        const float2* lp2 = reinterpret_cast<const float2*>(lm_pos + b * 18);
#pragma unroll
        for (int m = 0; m < 3; ++m) { px[m] = lp2[m].x; py[m] = lp2[m].y; }
    }

    // ---- pairwise distances ----
    float d01, d02, d12;
    {
        float dx, dy, sq;
        dx = px[0] - px[1]; dy = py[0] - py[1]; sq = dx * dx + dy * dy;
        d01 = sq > 0.f ? sqrtf(sq) : 0.f;
        dx = px[0] - px[2]; dy = py[0] - py[2]; sq = dx * dx + dy * dy;
        d02 = sq > 0.f ? sqrtf(sq) : 0.f;
        dx = px[1] - px[2]; dy = py[1] - py[2]; sq = dx * dx + dy * dy;
        d12 = sq > 0.f ? sqrtf(sq) : 0.f;
    }

    // ---- xl/xr for my 4 channels (weights scalar: CB uniform) ----
    float xl[3][4], xr[3][4];
#pragma unroll
    for (int j = 0; j < 3; ++j) {
        float xf[14];
        if (g == 0) {
            const float2 vel = reinterpret_cast<const float2*>(agent_vel + b * 6)[j];
            const float2* rl = reinterpret_cast<const float2*>(rel_lm + b * 18 + j * 6);
            const float4 op  = reinterpret_cast<const float4*>(other_pos + b * 12)[j];
            xf[0] = px[j]; xf[1] = py[j];
            xf[2] = vel.x; xf[3] = vel.y;
            xf[4] = rl[0].x; xf[5] = rl[0].y;
            xf[6] = rl[1].x; xf[7] = rl[1].y;
            xf[8] = rl[2].x; xf[9] = rl[2].y;
            xf[10] = op.x; xf[11] = op.y; xf[12] = op.z; xf[13] = op.w;
        } else {
            xf[0] = px[j]; xf[1] = py[j];
            xf[2] = 0.f;   xf[3] = 0.f;
#pragma unroll
            for (int m = 0; m < 3; ++m) {
                xf[4 + 2 * m] = px[m] - px[j];
                xf[5 + 2 * m] = py[m] - py[j];
            }
            const int a = o0[j], c2 = o1[j];
            xf[10] = px[a]  - px[j]; xf[11] = py[a]  - py[j];
            xf[12] = px[c2] - px[j]; xf[13] = py[c2] - py[j];
        }
#pragma unroll
        for (int cc = 0; cc < 4; ++cc) { xl[j][cc] = bl[CB + cc]; xr[j][cc] = br[CB + cc]; }
#pragma unroll
        for (int k = 0; k < 14; ++k) {
#pragma unroll
            for (int cc = 0; cc < 4; ++cc) {
                xl[j][cc] = fmaf(xf[k], Wl[k * 16 + CB + cc], xl[j][cc]);
                xr[j][cc] = fmaf(xf[k], Wr[k * 16 + CB + cc], xr[j][cc]);
            }
        }
    }

    // ---- per-channel-quarter logit partials for all 9 edges ----
    float lp[9];
#pragma unroll
    for (int i = 0; i < 3; ++i) {
#pragma unroll
        for (int j = 0; j < 3; ++j) {
            float axv, ayv, adv;
            if (i == j) {
                const int a = o0[i], c2 = o1[i];
                axv = 0.5f * (px[a] + px[c2]) - px[i];
                ayv = 0.5f * (py[a] + py[c2]) - py[i];
                const float dA = (i == 0) ? d01 : ((i == 1) ? d01 : d02);
                const float dB = (i == 0) ? d02 : ((i == 1) ? d12 : d12);
                adv = 0.5f * (dA + dB);
            } else {
                axv = px[j] - px[i];
                ayv = py[j] - py[i];
                adv = ((i == 0 && j == 1) || (i == 1 && j == 0)) ? d01
                    : ((i == 0 && j == 2) || (i == 2 && j == 0)) ? d02 : d12;
            }
            float acc = 0.f;
#pragma unroll
            for (int cc = 0; cc < 4; ++cc) {
                float gg = xl[j][cc] + xr[i][cc];
                gg = fmaf(axv, We[CB + cc], gg);
                gg = fmaf(ayv, We[16 + CB + cc], gg);
                gg = fmaf(adv, We[32 + CB + cc], gg);
                acc = fmaf(leaky(gg), att[CB + cc], acc);
            }
            lp[j * 3 + i] = acc;
        }
    }

    // ---- exchange partials across channel quarters ----
#pragma unroll
    for (int e = 0; e < 9; ++e) lds_lp[g][c4][lane][e] = lp[e];
    __syncthreads();    // B1: lp written, lds_o zeroed

    float lg[9];
#pragma unroll
    for (int e = 0; e < 9; ++e)
        lg[e] = lds_lp[g][0][lane][e] + lds_lp[g][1][lane][e]
              + lds_lp[g][2][lane][e] + lds_lp[g][3][lane][e];

    // ---- softmax per target + pooled relu-sum over my 4 channels ----
    float hs[4] = {0.f, 0.f, 0.f, 0.f};
#pragma unroll
    for (int i = 0; i < 3; ++i) {
        float m = fmaxf(lg[i], fmaxf(lg[3 + i], lg[6 + i]));
        float e0 = __expf(lg[i] - m);
        float e1 = __expf(lg[3 + i] - m);
        float e2 = __expf(lg[6 + i] - m);
        float inv = __builtin_amdgcn_rcpf(e0 + e1 + e2);
        float a0 = e0 * inv, a1 = e1 * inv, a2 = e2 * inv;
#pragma unroll
        for (int cc = 0; cc < 4; ++cc) {
            float v = fmaf(a0, xl[0][cc],
                      fmaf(a1, xl[1][cc],
                      fmaf(a2, xl[2][cc], bias[CB + cc])));
            hs[cc] += relu_f(v);
        }
    }

    // ---- publish pooled h: h[0..15]=agent(g0), h[16..31]=objective(g1) ----
#pragma unroll
    for (int cc = 0; cc < 4; ++cc) lds_h[lane][g * 16 + CB + cc] = hs[cc];
    __syncthreads();    // B2

    // ---- MLP: hidden units [q*16, q*16+16) for sample `lane` ----
    float z[16];
#pragma unroll
    for (int u = 0; u < 16; ++u) z[u] = b1[q * 16 + u];
    for (int k = 0; k < 32; ++k) {
        float hk = lds_h[lane][k];
#pragma unroll
        for (int u = 0; u < 16; ++u)
            z[u] = fmaf(hk, W1[k * 128 + q * 16 + u], z[u]);
    }
    float o[32];
#pragma unroll
    for (int c = 0; c < 32; ++c) o[c] = 0.f;
#pragma unroll
    for (int u = 0; u < 16; ++u) {
        float zz = relu_f(z[u]);
#pragma unroll
        for (int c = 0; c < 32; ++c)
            o[c] = fmaf(zz, W2[(q * 16 + u) * 32 + c], o[c]);
    }

    // ---- combine 8 partials per sample via LDS float atomics ----
#pragma unroll
    for (int c = 0; c < 32; ++c) atomicAdd(&lds_o[lane][c], o[c]);
    __syncthreads();    // B3

    // ---- final store: wave q stores channels [q*4, q*4+4) ----
    {
        const int bS = blockIdx.x * 64 + lane;
        if (bS < Btot) {
            float4 v;
            v.x = lds_o[lane][q * 4 + 0] + b2[q * 4 + 0];
            v.y = lds_o[lane][q * 4 + 1] + b2[q * 4 + 1];
            v.z = lds_o[lane][q * 4 + 2] + b2[q * 4 + 2];
            v.w = lds_o[lane][q * 4 + 3] + b2[q * 4 + 3];
            reinterpret_cast<float4*>(out)[bS * 8 + q] = v;
        }
    }
}

extern "C" void kernel_launch(void* const* d_in, const int* in_sizes, int n_in,
                              void* d_out, int out_size, void* d_ws, size_t ws_size,
                              hipStream_t stream) {
    const float* agent_pos = (const float*)d_in[0];
    const float* agent_vel = (const float*)d_in[1];
    const float* rel_lm    = (const float*)d_in[2];
    const float* other_pos = (const float*)d_in[3];
    const float* lm_pos    = (const float*)d_in[4];
    const float* Wl   = (const float*)d_in[5];
    const float* bl   = (const float*)d_in[6];
    const float* Wr   = (const float*)d_in[7];
    const float* br   = (const float*)d_in[8];
    const float* We   = (const float*)d_in[9];
    const float* att  = (const float*)d_in[10];
    const float* bias = (const float*)d_in[11];
    const float* W1   = (const float*)d_in[12];
    const float* b1   = (const float*)d_in[13];
    const float* W2   = (const float*)d_in[14];
    const float* b2   = (const float*)d_in[15];
    float* out = (float*)d_out;

    int B = in_sizes[0] / 6;                  // agent_pos is [B,3,2]
    int samplesPerBlock = 64;
    int grid = (B + samplesPerBlock - 1) / samplesPerBlock;
    scl_fused_kernel<<<grid, 512, 0, stream>>>(
        agent_pos, agent_vel, rel_lm, other_pos, lm_pos,
        Wl, bl, Wr, br, We, att, bias, W1, b1, W2, b2, out, B);
}

// Round 6
// 55.950 us; speedup vs baseline: 3.9303x; 3.9303x over previous
//
#include <hip/hip_runtime.h>

#define NEG_SLOPE 0.2f

typedef __bf16 bf16x8 __attribute__((ext_vector_type(8)));
typedef float  f32x4  __attribute__((ext_vector_type(4)));

__device__ __forceinline__ float leaky(float v)  { return v > 0.f ? v : NEG_SLOPE * v; }
__device__ __forceinline__ float relu_f(float v) { return v > 0.f ? v : 0.f; }

// Block = 256 threads = 4 waves, 64 samples/block.
// GAT phase : wave w -> g = w&1 (graph), ch = w>>1 (channel half: 8 ch each);
//             lane = sample-in-block. All weight indices uniform -> s_load.
//             Live set ~76 VGPR -> natural allocation, NO occupancy attributes
//             (R2-R4 lesson: every waves_per_eu/launch_bounds hint => 64-reg spill).
// MLP phase : MFMA 16x16x32 bf16. Wave w owns M-tile (samples w*16..w*16+15).
//             L1: A from lds_h (bf16, stride 40 -> 2-way banks), B from global W1
//             (fp32->bf16 cvt, L2-hot). z -> per-wave private LDS (NO barrier:
//             same-wave write->read, compiler inserts lgkmcnt). L2: 4 K-steps.
// Barriers: 2 total.
__global__ __launch_bounds__(256)
void scl_fused_kernel(
    const float* __restrict__ agent_pos, const float* __restrict__ agent_vel,
    const float* __restrict__ rel_lm, const float* __restrict__ other_pos,
    const float* __restrict__ lm_pos,
    const float* __restrict__ Wl, const float* __restrict__ bl,
    const float* __restrict__ Wr, const float* __restrict__ br,
    const float* __restrict__ We, const float* __restrict__ att,
    const float* __restrict__ bias,
    const float* __restrict__ W1, const float* __restrict__ b1,
    const float* __restrict__ W2, const float* __restrict__ b2,
    float* __restrict__ out, int Btot)
{
    __shared__ float lds_lp[2][2][64][9];              // [g][ch][sample][edge] logit partials
    __shared__ alignas(16) __bf16 lds_h[64][40];       // pooled GAT out, stride 40 bf16 = 80B
    __shared__ alignas(16) __bf16 lds_z[4][16][136];   // per-wave z, stride 136 bf16 = 272B

    const int tid  = threadIdx.x;
    const int lane = tid & 63;                         // sample-in-block
    const int w    = tid >> 6;
    const int g    = __builtin_amdgcn_readfirstlane(w & 1);
    const int ch   = __builtin_amdgcn_readfirstlane((w >> 1) & 1);
    const int wu   = __builtin_amdgcn_readfirstlane(w);
    const int CB   = ch * 8;                           // channel base (uniform)

    int b = blockIdx.x * 64 + lane;
    if (b >= Btot) b = Btot - 1;                       // clamp reads; barriers stay uniform

    const int o0[3] = {1, 0, 0};
    const int o1[3] = {2, 2, 1};

    // ---- positions (uniform branch) ----
    float px[3], py[3];
    if (g == 0) {
        const float2* ap = reinterpret_cast<const float2*>(agent_pos + b * 6);
#pragma unroll
        for (int j = 0; j < 3; ++j) { px[j] = ap[j].x; py[j] = ap[j].y; }
    } else {
        const float2* lp2 = reinterpret_cast<const float2*>(lm_pos + b * 18);
#pragma unroll
        for (int m = 0; m < 3; ++m) { px[m] = lp2[m].x; py[m] = lp2[m].y; }
    }

    // ---- pairwise distances ----
    float d01, d02, d12;
    {
        float dx, dy, sq;
        dx = px[0] - px[1]; dy = py[0] - py[1]; sq = dx * dx + dy * dy;
        d01 = sq > 0.f ? sqrtf(sq) : 0.f;
        dx = px[0] - px[2]; dy = py[0] - py[2]; sq = dx * dx + dy * dy;
        d02 = sq > 0.f ? sqrtf(sq) : 0.f;
        dx = px[1] - px[2]; dy = py[1] - py[2]; sq = dx * dx + dy * dy;
        d12 = sq > 0.f ? sqrtf(sq) : 0.f;
    }

    // ---- xl/xr for my 8 channels (weights scalar: CB uniform) ----
    float xl[3][8], xr[3][8];
#pragma unroll
    for (int j = 0; j < 3; ++j) {
        float xf[14];
        if (g == 0) {
            const float2 vel = reinterpret_cast<const float2*>(agent_vel + b * 6)[j];
            const float2* rl = reinterpret_cast<const float2*>(rel_lm + b * 18 + j * 6);
            const float4 op  = reinterpret_cast<const float4*>(other_pos + b * 12)[j];
            xf[0] = px[j]; xf[1] = py[j];
            xf[2] = vel.x; xf[3] = vel.y;
            xf[4] = rl[0].x; xf[5] = rl[0].y;
            xf[6] = rl[1].x; xf[7] = rl[1].y;
            xf[8] = rl[2].x; xf[9] = rl[2].y;
            xf[10] = op.x; xf[11] = op.y; xf[12] = op.z; xf[13] = op.w;
        } else {
            xf[0] = px[j]; xf[1] = py[j];
            xf[2] = 0.f;   xf[3] = 0.f;
#pragma unroll
            for (int m = 0; m < 3; ++m) {
                xf[4 + 2 * m] = px[m] - px[j];
                xf[5 + 2 * m] = py[m] - py[j];
            }
            const int a = o0[j], c2 = o1[j];
            xf[10] = px[a]  - px[j]; xf[11] = py[a]  - py[j];
            xf[12] = px[c2] - px[j]; xf[13] = py[c2] - py[j];
        }
#pragma unroll
        for (int cc = 0; cc < 8; ++cc) { xl[j][cc] = bl[CB + cc]; xr[j][cc] = br[CB + cc]; }
#pragma unroll
        for (int k = 0; k < 14; ++k) {
#pragma unroll
            for (int cc = 0; cc < 8; ++cc) {
                xl[j][cc] = fmaf(xf[k], Wl[k * 16 + CB + cc], xl[j][cc]);
                xr[j][cc] = fmaf(xf[k], Wr[k * 16 + CB + cc], xr[j][cc]);
            }
        }
    }

    // ---- logit partials over my 8 channels, all 9 edges ----
    float lp[9];
#pragma unroll
    for (int i = 0; i < 3; ++i) {
#pragma unroll
        for (int j = 0; j < 3; ++j) {
            float axv, ayv, adv;
            if (i == j) {
                const int a = o0[i], c2 = o1[i];
                axv = 0.5f * (px[a] + px[c2]) - px[i];
                ayv = 0.5f * (py[a] + py[c2]) - py[i];
                const float dA = (i == 0) ? d01 : ((i == 1) ? d01 : d02);
                const float dB = (i == 0) ? d02 : ((i == 1) ? d12 : d12);
                adv = 0.5f * (dA + dB);
            } else {
                axv = px[j] - px[i];
                ayv = py[j] - py[i];
                adv = ((i == 0 && j == 1) || (i == 1 && j == 0)) ? d01
                    : ((i == 0 && j == 2) || (i == 2 && j == 0)) ? d02 : d12;
            }
            float acc = 0.f;
#pragma unroll
            for (int cc = 0; cc < 8; ++cc) {
                float gg = xl[j][cc] + xr[i][cc];
                gg = fmaf(axv, We[CB + cc], gg);
                gg = fmaf(ayv, We[16 + CB + cc], gg);
                gg = fmaf(adv, We[32 + CB + cc], gg);
                acc = fmaf(leaky(gg), att[CB + cc], acc);
            }
            lp[j * 3 + i] = acc;
        }
    }

    // ---- exchange partials with sibling channel-half ----
#pragma unroll
    for (int e = 0; e < 9; ++e) lds_lp[g][ch][lane][e] = lp[e];
    __syncthreads();    // B1

    float lg[9];
#pragma unroll
    for (int e = 0; e < 9; ++e) lg[e] = lp[e] + lds_lp[g][1 - ch][lane][e];

    // ---- softmax per target + pooled relu-sum over my 8 channels ----
    float hs[8] = {0.f, 0.f, 0.f, 0.f, 0.f, 0.f, 0.f, 0.f};
#pragma unroll
    for (int i = 0; i < 3; ++i) {
        float m = fmaxf(lg[i], fmaxf(lg[3 + i], lg[6 + i]));
        float e0 = __expf(lg[i] - m);
        float e1 = __expf(lg[3 + i] - m);
        float e2 = __expf(lg[6 + i] - m);
        float inv = __builtin_amdgcn_rcpf(e0 + e1 + e2);
        float a0 = e0 * inv, a1 = e1 * inv, a2 = e2 * inv;
#pragma unroll
        for (int cc = 0; cc < 8; ++cc) {
            float v = fmaf(a0, xl[0][cc],
                      fmaf(a1, xl[1][cc],
                      fmaf(a2, xl[2][cc], bias[CB + cc])));
            hs[cc] += relu_f(v);
        }
    }

    // ---- publish pooled h as bf16: h[0..15]=agent(g0), h[16..31]=objective(g1) ----
    {
        bf16x8 hv;
#pragma unroll
        for (int cc = 0; cc < 8; ++cc) hv[cc] = (__bf16)hs[cc];
        *reinterpret_cast<bf16x8*>(&lds_h[lane][g * 16 + CB]) = hv;   // 16B-aligned
    }
    __syncthreads();    // B2

    // ================= MLP via MFMA 16x16x32 bf16 =================
    const int l15 = lane & 15;
    const int l4  = lane >> 4;          // 0..3 (K-chunk / row-quad selector)
    const int Mrow0 = wu * 16;          // wave's M-tile base (sample-in-block)
    const f32x4 zero4 = {0.f, 0.f, 0.f, 0.f};

    // ---- layer 1: z[16x128] = h[16x32] @ W1[32x128] + b1, relu ----
    // A-frag: lane holds A[l15][l4*8 + j], j=0..7
    bf16x8 a1 = *reinterpret_cast<const bf16x8*>(&lds_h[Mrow0 + l15][l4 * 8]);

#pragma unroll
    for (int n = 0; n < 8; ++n) {
        // B-frag: lane holds B[l4*8 + j][n*16 + l15]
        bf16x8 bf;
        const float* Wcol = W1 + (l4 * 8) * 128 + n * 16 + l15;
#pragma unroll
        for (int j = 0; j < 8; ++j) bf[j] = (__bf16)Wcol[j * 128];
        f32x4 acc = __builtin_amdgcn_mfma_f32_16x16x32_bf16(a1, bf, zero4, 0, 0, 0);
        float b1v = b1[n * 16 + l15];
        // C layout: lane holds D[l4*4 + r][n*16 + l15]
#pragma unroll
        for (int r = 0; r < 4; ++r)
            lds_z[wu][l4 * 4 + r][n * 16 + l15] = (__bf16)relu_f(acc[r] + b1v);
    }
    // per-wave private z buffer: same-wave write->read, no barrier needed
    // (compiler inserts lgkmcnt wait before dependent ds_read)

    // ---- layer 2: o[16x32] = z[16x128] @ W2[128x32] + b2 ----
    f32x4 acc2[2] = {zero4, zero4};
#pragma unroll
    for (int ks = 0; ks < 4; ++ks) {
        bf16x8 a2 = *reinterpret_cast<const bf16x8*>(&lds_z[wu][l15][ks * 32 + l4 * 8]);
#pragma unroll
        for (int n = 0; n < 2; ++n) {
            bf16x8 bf;
            const float* Wcol = W2 + (ks * 32 + l4 * 8) * 32 + n * 16 + l15;
#pragma unroll
            for (int j = 0; j < 8; ++j) bf[j] = (__bf16)Wcol[j * 32];
            acc2[n] = __builtin_amdgcn_mfma_f32_16x16x32_bf16(a2, bf, acc2[n], 0, 0, 0);
        }
    }

    // ---- store: lane holds o[l4*4 + r][n*16 + l15] ----
#pragma unroll
    for (int n = 0; n < 2; ++n) {
        float b2v = b2[n * 16 + l15];
#pragma unroll
        for (int r = 0; r < 4; ++r) {
            int row = blockIdx.x * 64 + Mrow0 + l4 * 4 + r;
            if (row < Btot)
                out[row * 32 + n * 16 + l15] = acc2[n][r] + b2v;
        }
    }
}

extern "C" void kernel_launch(void* const* d_in, const int* in_sizes, int n_in,
                              void* d_out, int out_size, void* d_ws, size_t ws_size,
                              hipStream_t stream) {
    const float* agent_pos = (const float*)d_in[0];
    const float* agent_vel = (const float*)d_in[1];
    const float* rel_lm    = (const float*)d_in[2];
    const float* other_pos = (const float*)d_in[3];
    const float* lm_pos    = (const float*)d_in[4];
    const float* Wl   = (const float*)d_in[5];
    const float* bl   = (const float*)d_in[6];
    const float* Wr   = (const float*)d_in[7];
    const float* br   = (const float*)d_in[8];
    const float* We   = (const float*)d_in[9];
    const float* att  = (const float*)d_in[10];
    const float* bias = (const float*)d_in[11];
    const float* W1   = (const float*)d_in[12];
    const float* b1   = (const float*)d_in[13];
    const float* W2   = (const float*)d_in[14];
    const float* b2   = (const float*)d_in[15];
    float* out = (float*)d_out;

    int B = in_sizes[0] / 6;                  // agent_pos is [B,3,2]
    int samplesPerBlock = 64;
    int grid = (B + samplesPerBlock - 1) / samplesPerBlock;
    scl_fused_kernel<<<grid, 256, 0, stream>>>(
        agent_pos, agent_vel, rel_lm, other_pos, lm_pos,
        Wl, bl, Wr, br, We, att, bias, W1, b1, W2, b2, out, B);
}